// Round 7
// baseline (285.295 us; speedup 1.0000x reference)
//
#include <hip/hip_runtime.h>
#include <stdint.h>

// ============================================================================
// MessagePassing collapse:
//   e2 = (3+a_vc)*base,  base = LN((scores*softmax_e(scores)) @ Wp_vc^T)
//   n2 = (1+a)^3 * features + (1-a)((1+a)^2+(1+a)+1) * nb,  a = ec_alpha
//   nb = LN((inc @ base) @ Wp_ec^T)  (LN positive-scale-invariant)
//   EC's MHA is dead code.
// R7: WM=4 (128-row tiles) for scores / W0 / out-proj GEMMs (compute-bound,
// intermediates are L3-resident — tile ladder says 128-tile ~2x 64-tile MFMA
// efficiency). PART partials 24->12. attn s32 loop unroll 2. 8 dispatches.
// ============================================================================

#define DEV static __device__ __forceinline__

typedef __attribute__((ext_vector_type(8))) short bf16x8;
typedef __attribute__((ext_vector_type(4))) float f32x4;

DEV uint16_t f2bf(float x){
  union{float f; uint32_t u;} v; v.f=x;
  uint32_t r = v.u + 0x7fffu + ((v.u>>16)&1u);
  return (uint16_t)(r>>16);
}
DEV float bf2f(uint16_t b){
  union{uint32_t u; float f;} v; v.u=((uint32_t)b)<<16; return v.f;
}

#if __has_builtin(__builtin_amdgcn_global_load_lds)
#define HAVE_GLL 1
#else
#define HAVE_GLL 0
#endif

DEV void load_lds16(const uint16_t* g, void* l){
#if HAVE_GLL
  __builtin_amdgcn_global_load_lds((const __attribute__((address_space(1))) uint32_t*)g,
                                   (__attribute__((address_space(3))) uint32_t*)l, 16, 0, 0);
#else
  *(bf16x8*)l = *(const bf16x8*)g;
#endif
}

// ---------------------------------------------------------------------------
// merged prep: blocks [0,12288) = inc prep (f32 copy out + bf16 + bf16^T);
// blocks [12288,14720) = f32->bf16 casts of features + 4 weights.
// ---------------------------------------------------------------------------
__global__ __launch_bounds__(256)
void prep(const float* __restrict__ inc, float* __restrict__ out_inc,
          uint16_t* __restrict__ incb, uint16_t* __restrict__ incT,
          const float* __restrict__ feats, const float* __restrict__ win,
          const float* __restrict__ wout, const float* __restrict__ wpv,
          const float* __restrict__ wpe,
          uint16_t* __restrict__ xb, uint16_t* __restrict__ ow,
          uint16_t* __restrict__ oo, uint16_t* __restrict__ ov,
          uint16_t* __restrict__ oe){
  __shared__ float T[32][33];
  int bx = blockIdx.x;
  int tid = threadIdx.x;
  if (bx < 12288){
    int x = bx % 48;           // e tile
    int t = bx / 48;
    int y = t % 32;            // m tile
    int b = t / 32;            // batch
    int c0 = x*32, r0 = y*32;
    int tx = tid & 31, ty = tid >> 5;
    size_t base = (size_t)b*1024*1536;
#pragma unroll
    for (int j=0;j<4;++j){
      int r = r0 + ty + j*8;
      size_t idx = base + (size_t)r*1536 + c0 + tx;
      float v = inc[idx];
      T[ty+j*8][tx] = v;
      out_inc[idx] = v;
      incb[idx] = f2bf(v);
    }
    __syncthreads();
    size_t baseT = (size_t)b*1536*1024;
#pragma unroll
    for (int j=0;j<4;++j){
      int c = c0 + ty + j*8;
      incT[baseT + (size_t)c*1024 + r0 + tx] = f2bf(T[tx][ty+j*8]);
    }
  } else {
    int i = (bx - 12288)*256 + tid;   // i4 units, total 622592
    const float* src; uint16_t* dst; int j;
    if (i < 524288){ src=feats; dst=xb; j=i; }
    else {
      i -= 524288;
      if (i < 49152){ src=win; dst=ow; j=i; }
      else if (i < 65536){ src=wout; dst=oo; j=i-49152; }
      else if (i < 81920){ src=wpv; dst=ov; j=i-65536; }
      else { src=wpe; dst=oe; j=i-81920; }
    }
    float4 v = ((const float4*)src)[j];
    union { uint16_t u[4]; uint64_t q; } p;
    p.u[0]=f2bf(v.x); p.u[1]=f2bf(v.y); p.u[2]=f2bf(v.z); p.u[3]=f2bf(v.w);
    ((uint64_t*)dst)[j] = p.q;
  }
}

// ---------------------------------------------------------------------------
// NT bf16 GEMM: C[M,N] = A[M,K] * B[N,K]^T (+bias).
// WM: rows/wave = WM*16, M-tile = WM*32. N-tile 128. 256 thr (2x2 waves).
// EPI: 0 = plain (Cf f32 / Cb bf16 row-major)
//      1 = transposed bf16 store (per-batch [N][1024] from flat M=8*1024)
//      2 = row-major store + per-block column exp-sum partials (write-only)
// ---------------------------------------------------------------------------
template<int WM, int BK, int EPI>
__global__ __launch_bounds__(256, 3)
void gemm_nt(const uint16_t* __restrict__ A, const uint16_t* __restrict__ B,
             float* __restrict__ Cf, uint16_t* __restrict__ Cb,
             const float* __restrict__ bias,
             int M, int N, int K, long sA, long sB, long sC,
             float* __restrict__ extra){
  constexpr int AROWS = WM*32;
  constexpr int UPR = BK/8;        // 16B units per row
  constexpr int RPP = 256/UPR;     // rows staged per pass
  __shared__ short As[AROWS*BK];
  __shared__ short Bs[128*BK];
  const int tid = threadIdx.x;
  const int lane = tid & 63;
  const int w = tid >> 6;
  const int wm = w & 1, wn = w >> 1;
  const int r = lane & 15, q = lane >> 4;
  const long zb = blockIdx.z;
  const uint16_t* Ab = A + zb*sA + (size_t)(blockIdx.x*AROWS)*K;
  const uint16_t* Bb = B + zb*sB + (size_t)(blockIdx.y*128)*K;
  f32x4 acc[WM][4];
#pragma unroll
  for (int i=0;i<WM;++i)
#pragma unroll
    for (int j=0;j<4;++j) acc[i][j] = (f32x4){0.f,0.f,0.f,0.f};

  const int srow = tid / UPR;
  const int sblk = tid % UPR;

  for (int kb = 0; kb < K; kb += BK){
#pragma unroll
    for (int i=0;i<AROWS/RPP;++i){
      int row = srow + RPP*i;
      int lblk = sblk ^ (row & (UPR-1));
      load_lds16(Ab + (size_t)row*K + kb + lblk*8, (char*)As + i*4096 + tid*16);
    }
#pragma unroll
    for (int i=0;i<128/RPP;++i){
      int row = srow + RPP*i;
      int lblk = sblk ^ (row & (UPR-1));
      load_lds16(Bb + (size_t)row*K + kb + lblk*8, (char*)Bs + i*4096 + tid*16);
    }
    __syncthreads();
#pragma unroll
    for (int kc=0;kc<BK/32;++kc){
      bf16x8 af[WM], bf[4];
#pragma unroll
      for (int mt=0;mt<WM;++mt){
        int m = wm*(WM*16) + mt*16 + r;
        af[mt] = *(const bf16x8*)&As[m*BK + ((kc*4 + q) ^ (m&(UPR-1)))*8];
      }
#pragma unroll
      for (int nt=0;nt<4;++nt){
        int n = wn*64 + nt*16 + r;
        bf[nt] = *(const bf16x8*)&Bs[n*BK + ((kc*4 + q) ^ (n&(UPR-1)))*8];
      }
#pragma unroll
      for (int mt=0;mt<WM;++mt)
#pragma unroll
        for (int nt=0;nt<4;++nt)
          acc[mt][nt] = __builtin_amdgcn_mfma_f32_16x16x32_bf16(af[mt], bf[nt], acc[mt][nt], 0,0,0);
    }
    __syncthreads();
  }

  const int gm0 = blockIdx.x*AROWS + wm*(WM*16);
  const int gn0 = blockIdx.y*128 + wn*64;

  if constexpr (EPI == 1){
    // transposed bf16: out[b][gn][m'] with b = gm>>10, m' = gm&1023
#pragma unroll
    for (int mt=0;mt<WM;++mt){
      int gmb = gm0 + mt*16 + q*4;           // 4 consecutive rows via reg
      size_t bb_ = (size_t)(gmb>>10)*(256*1024);
      int mm = gmb & 1023;
#pragma unroll
      for (int nt=0;nt<4;++nt){
        int gn = gn0 + nt*16 + r;
        float bv = bias ? bias[gn] : 0.f;
        union{uint16_t u[4]; uint64_t q64;} pk;
#pragma unroll
        for (int reg=0;reg<4;++reg) pk.u[reg] = f2bf(acc[mt][nt][reg] + bv);
        *(uint64_t*)(Cb + bb_ + (size_t)gn*1024 + mm) = pk.q64;
      }
    }
  } else {
#pragma unroll
    for (int mt=0;mt<WM;++mt){
#pragma unroll
      for (int nt=0;nt<4;++nt){
        int gn = gn0 + nt*16 + r;
        float bv = bias ? bias[gn] : 0.f;
#pragma unroll
        for (int reg=0;reg<4;++reg){
          int gm = gm0 + mt*16 + q*4 + reg;   // C/D: col=lane&15, row=quad*4+reg
          float v = acc[mt][nt][reg] + bv;
          size_t off = (size_t)(zb*sC) + (size_t)gm*N + gn;
          if (Cf) Cf[off] = v;
          if (Cb) Cb[off] = f2bf(v);
        }
      }
    }
    if constexpr (EPI == 2){
      // per-block column sums of exp(score) -> extra[(zb*gridDim.x+bx)*256+gn]
      __shared__ float colsum[2][128];
#pragma unroll
      for (int nt=0;nt<4;++nt){
        float s = 0.f;
#pragma unroll
        for (int mt=0;mt<WM;++mt)
#pragma unroll
          for (int reg=0;reg<4;++reg) s += __expf(acc[mt][nt][reg]);
        s += __shfl_xor(s, 16);
        s += __shfl_xor(s, 32);
        if (q == 0) colsum[wm][wn*64 + nt*16 + r] = s;
      }
      __syncthreads();
      if (tid < 128){
        float v = colsum[0][tid] + colsum[1][tid];
        extra[((size_t)zb*gridDim.x + blockIdx.x)*256 + blockIdx.y*128 + tid] = v;
      }
    }
  }
}

// ---------------------------------------------------------------------------
// Edge path: A = p(scores) with p = v*exp(v)/L computed during staging;
// L folded from PART (12 partials/batch) in-kernel. GEMM vs Wpv^T + LN.
// Tile 64m x 256n, BK=64, 512 thr. Writes out_edge f32 + BASET bf16 [b][d][e].
// ---------------------------------------------------------------------------
__global__ __launch_bounds__(512, 4)
void gemm_ln_edge(const uint16_t* __restrict__ SB, const uint16_t* __restrict__ B,
                  const float* __restrict__ part, const float* __restrict__ g,
                  const float* __restrict__ bb, const float* __restrict__ alpha,
                  float* __restrict__ out, uint16_t* __restrict__ baset){
  __shared__ short As[64*64];
  __shared__ short Bs[256*64];
  __shared__ float lnS[4][64], lnQ[4][64];
  __shared__ float PLinv[256];
  __shared__ float Phalf[2][256];
  const int tid = threadIdx.x;
  const int lane = tid & 63;
  const int w = tid >> 6;
  const int wm = w & 1;
  const int wn2 = w >> 1;
  const int r = lane & 15, q = lane >> 4;
  const int batch = blockIdx.x / 24;

  // fold 12 PART partials -> 1/L (in LDS)
  {
    int d = tid & 255, h = tid >> 8;
    float s = 0.f;
#pragma unroll
    for (int i=0;i<6;++i) s += part[((size_t)batch*12 + h*6 + i)*256 + d];
    Phalf[h][d] = s;
  }
  __syncthreads();
  if (tid < 256) PLinv[tid] = 1.0f / (Phalf[0][tid] + Phalf[1][tid]);
  __syncthreads();

  f32x4 acc[2][4];
#pragma unroll
  for (int i=0;i<2;++i)
#pragma unroll
    for (int j=0;j<4;++j) acc[i][j] = (f32x4){0.f,0.f,0.f,0.f};

  const int srow = tid >> 3;   // 0..63
  const int sblk = tid & 7;

  for (int kb = 0; kb < 256; kb += 64){
    // A stage with softmax-apply transform (VGPR path)
    {
      bf16x8 v = *(const bf16x8*)(SB + (size_t)(blockIdx.x*64 + srow)*256 + kb + sblk*8);
      const float* Lp = &PLinv[kb + sblk*8];
      bf16x8 pv;
#pragma unroll
      for (int j=0;j<8;++j){
        float x = bf2f((uint16_t)v[j]);
        pv[j] = (short)f2bf(x * __expf(x) * Lp[j]);
      }
      *(bf16x8*)&As[srow*64 + (sblk ^ (srow&7))*8] = pv;
    }
#pragma unroll
    for (int i=0;i<4;++i){
      int row = srow + 64*i;
      int lblk = sblk ^ (row & 7);
      load_lds16(B + (size_t)row*256 + kb + lblk*8, (char*)Bs + i*8192 + tid*16);
    }
    __syncthreads();
#pragma unroll
    for (int kc=0;kc<2;++kc){
      bf16x8 af[2], bf[4];
#pragma unroll
      for (int mt=0;mt<2;++mt){
        int m = wm*32 + mt*16 + r;
        af[mt] = *(const bf16x8*)&As[m*64 + ((kc*4 + q) ^ (m&7))*8];
      }
#pragma unroll
      for (int nt=0;nt<4;++nt){
        int n = wn2*64 + nt*16 + r;
        bf[nt] = *(const bf16x8*)&Bs[n*64 + ((kc*4 + q) ^ (n&7))*8];
      }
#pragma unroll
      for (int mt=0;mt<2;++mt)
#pragma unroll
        for (int nt=0;nt<4;++nt)
          acc[mt][nt] = __builtin_amdgcn_mfma_f32_16x16x32_bf16(af[mt], bf[nt], acc[mt][nt], 0,0,0);
    }
    __syncthreads();
  }

  // cross-wave LN reduction
  float rs[2][4], rq[2][4];
#pragma unroll
  for (int mt=0;mt<2;++mt)
#pragma unroll
    for (int reg=0;reg<4;++reg){
      float s=0.f, s2=0.f;
#pragma unroll
      for (int nt=0;nt<4;++nt){
        float v = acc[mt][nt][reg];
        s += v; s2 += v*v;
      }
#pragma unroll
      for (int off=1; off<16; off<<=1){ s += __shfl_xor(s,off); s2 += __shfl_xor(s2,off); }
      rs[mt][reg]=s; rq[mt][reg]=s2;
    }
  if (r == 0){
#pragma unroll
    for (int mt=0;mt<2;++mt)
#pragma unroll
      for (int reg=0;reg<4;++reg){
        int row = wm*32 + mt*16 + q*4 + reg;
        lnS[wn2][row] = rs[mt][reg];
        lnQ[wn2][row] = rq[mt][reg];
      }
  }
  __syncthreads();

  const float c0 = 3.0f + alpha[0];
  float mu_[2][4], rstd_[2][4];
#pragma unroll
  for (int mt=0;mt<2;++mt)
#pragma unroll
    for (int reg=0;reg<4;++reg){
      int row = wm*32 + mt*16 + q*4 + reg;
      float S = lnS[0][row]+lnS[1][row]+lnS[2][row]+lnS[3][row];
      float Q = lnQ[0][row]+lnQ[1][row]+lnQ[2][row]+lnQ[3][row];
      float mu = S * (1.f/256.f);
      float var = fmaxf(Q*(1.f/256.f) - mu*mu, 0.f);
      mu_[mt][reg] = mu;
      rstd_[mt][reg] = rsqrtf(var + 1e-5f);
    }

  int e0 = (blockIdx.x % 24) * 64 + wm*32;
#pragma unroll
  for (int mt=0;mt<2;++mt){
#pragma unroll
    for (int nt=0;nt<4;++nt){
      int gn = wn2*64 + nt*16 + r;
      float gv = g[gn], bv = bb[gn];
      union{uint16_t u[4]; uint64_t q64;} pk;
#pragma unroll
      for (int reg=0;reg<4;++reg){
        int row = wm*32 + mt*16 + q*4 + reg;
        size_t gm = (size_t)blockIdx.x*64 + row;
        float o = ((acc[mt][nt][reg]-mu_[mt][reg])*rstd_[mt][reg]*gv + bv) * c0;
        pk.u[reg] = f2bf(o);
        out[gm*256 + gn] = o;
      }
      int ee = e0 + mt*16 + q*4;
      *(uint64_t*)(baset + ((size_t)batch*256 + gn)*1536 + ee) = pk.q64;
    }
  }
}

// ---------------------------------------------------------------------------
// GEMM + LN/blend (node path): out = cf*feat + cn*LN(A@B^T). 64x256, K=256.
// ---------------------------------------------------------------------------
__global__ __launch_bounds__(512, 4)
void gemm_ln_node(const uint16_t* __restrict__ A, const uint16_t* __restrict__ B,
                  const float* __restrict__ g, const float* __restrict__ bb,
                  const float* __restrict__ alpha, const float* __restrict__ feats,
                  float* __restrict__ out){
  __shared__ short As[64*64];
  __shared__ short Bs[256*64];
  __shared__ float lnS[4][64], lnQ[4][64];
  const int tid = threadIdx.x;
  const int lane = tid & 63;
  const int w = tid >> 6;
  const int wm = w & 1;
  const int wn2 = w >> 1;
  const int r = lane & 15, q = lane >> 4;
  const uint16_t* Ab = A + (size_t)(blockIdx.x*64)*256;
  f32x4 acc[2][4];
#pragma unroll
  for (int i=0;i<2;++i)
#pragma unroll
    for (int j=0;j<4;++j) acc[i][j] = (f32x4){0.f,0.f,0.f,0.f};

  const int srow = tid >> 3;
  const int sblk = tid & 7;

  for (int kb = 0; kb < 256; kb += 64){
    {
      int lblk = sblk ^ (srow & 7);
      load_lds16(Ab + (size_t)srow*256 + kb + lblk*8, (char*)As + tid*16);
    }
#pragma unroll
    for (int i=0;i<4;++i){
      int row = srow + 64*i;
      int lblk = sblk ^ (row & 7);
      load_lds16(B + (size_t)row*256 + kb + lblk*8, (char*)Bs + i*8192 + tid*16);
    }
    __syncthreads();
#pragma unroll
    for (int kc=0;kc<2;++kc){
      bf16x8 af[2], bf[4];
#pragma unroll
      for (int mt=0;mt<2;++mt){
        int m = wm*32 + mt*16 + r;
        af[mt] = *(const bf16x8*)&As[m*64 + ((kc*4 + q) ^ (m&7))*8];
      }
#pragma unroll
      for (int nt=0;nt<4;++nt){
        int n = wn2*64 + nt*16 + r;
        bf[nt] = *(const bf16x8*)&Bs[n*64 + ((kc*4 + q) ^ (n&7))*8];
      }
#pragma unroll
      for (int mt=0;mt<2;++mt)
#pragma unroll
        for (int nt=0;nt<4;++nt)
          acc[mt][nt] = __builtin_amdgcn_mfma_f32_16x16x32_bf16(af[mt], bf[nt], acc[mt][nt], 0,0,0);
    }
    __syncthreads();
  }

  float rs[2][4], rq[2][4];
#pragma unroll
  for (int mt=0;mt<2;++mt)
#pragma unroll
    for (int reg=0;reg<4;++reg){
      float s=0.f, s2=0.f;
#pragma unroll
      for (int nt=0;nt<4;++nt){
        float v = acc[mt][nt][reg];
        s += v; s2 += v*v;
      }
#pragma unroll
      for (int off=1; off<16; off<<=1){ s += __shfl_xor(s,off); s2 += __shfl_xor(s2,off); }
      rs[mt][reg]=s; rq[mt][reg]=s2;
    }
  if (r == 0){
#pragma unroll
    for (int mt=0;mt<2;++mt)
#pragma unroll
      for (int reg=0;reg<4;++reg){
        int row = wm*32 + mt*16 + q*4 + reg;
        lnS[wn2][row] = rs[mt][reg];
        lnQ[wn2][row] = rq[mt][reg];
      }
  }
  __syncthreads();

  const float a = alpha[0];
  const float ap1 = 1.f + a;
  const float cn = (1.f - a)*(ap1*ap1 + ap1 + 1.f);
  const float cf = ap1*ap1*ap1;

#pragma unroll
  for (int mt=0;mt<2;++mt){
#pragma unroll
    for (int reg=0;reg<4;++reg){
      int row = wm*32 + mt*16 + q*4 + reg;
      float S = lnS[0][row]+lnS[1][row]+lnS[2][row]+lnS[3][row];
      float Q = lnQ[0][row]+lnQ[1][row]+lnQ[2][row]+lnQ[3][row];
      float mu = S * (1.f/256.f);
      float var = fmaxf(Q*(1.f/256.f) - mu*mu, 0.f);
      float rstd = rsqrtf(var + 1e-5f);
      size_t gm = (size_t)blockIdx.x*64 + row;
#pragma unroll
      for (int nt=0;nt<4;++nt){
        int gn = wn2*64 + nt*16 + r;
        float nv = (acc[mt][nt][reg]-mu)*rstd*g[gn] + bb[gn];
        out[gm*256 + gn] = cf*feats[gm*256+gn] + cn*nv;
      }
    }
  }
}

// ---------------------------------------------------------------------------
// Attention: S^T = K*Q^T (A/B frags interchangeable), packed b64 P-store,
// scalar l. 512 thr = 8 waves x 16 q-rows. grid (8, 64). Max-free softmax.
// ---------------------------------------------------------------------------
DEV void stage_K(short* Kl, const uint16_t* __restrict__ qkv, size_t rowbase,
                 int c, int h, int kr){
  const uint16_t* kp = qkv + ((rowbase + c*256 + kr)*768 + 256 + h*32);
  int sz = (kr&3) ^ ((kr>>2)&1);
#pragma unroll
  for (int lb=0; lb<4; ++lb){
    bf16x8 v = *(const bf16x8*)(kp + lb*8);
    *(bf16x8*)&Kl[kr*32 + ((lb ^ sz))*8] = v;
  }
}

DEV void stage_V(short* VT, const uint16_t* __restrict__ qkv, size_t rowbase,
                 int c, int h, int t){
  int kvp = (t>>1)*2;
  int dhh = (t&1)*16;
  const uint16_t* v0 = qkv + ((rowbase + c*256 + kvp)*768 + 512 + h*32 + dhh);
  const uint16_t* v1 = v0 + 768;
  bf16x8 a0 = *(const bf16x8*)(v0);
  bf16x8 a1 = *(const bf16x8*)(v0+8);
  bf16x8 b0 = *(const bf16x8*)(v1);
  bf16x8 b1 = *(const bf16x8*)(v1+8);
  int blkbase = kvp>>3, off = kvp&7;
#pragma unroll
  for (int i=0;i<8;++i){
    int dh = dhh + i;
    uint32_t pack = (uint32_t)(uint16_t)a0[i] | ((uint32_t)(uint16_t)b0[i]<<16);
    *(uint32_t*)&VT[dh*256 + ((blkbase ^ (dh&7))*8) + off] = pack;
  }
#pragma unroll
  for (int i=0;i<8;++i){
    int dh = dhh + 8 + i;
    uint32_t pack = (uint32_t)(uint16_t)a1[i] | ((uint32_t)(uint16_t)b1[i]<<16);
    *(uint32_t*)&VT[dh*256 + ((blkbase ^ (dh&7))*8) + off] = pack;
  }
}

__global__ __launch_bounds__(512)
void attn_fwd(const uint16_t* __restrict__ qkv, uint16_t* __restrict__ O){
  __shared__ short Kl[256*32];
  __shared__ short VT[32*256];
  __shared__ short Pl[8][16*36];
  const int tid = threadIdx.x, lane = tid&63, w = tid>>6;
  const int r = lane&15, q = lane>>4;
  const int bh = blockIdx.y, b = bh>>3, h = bh&7;
  const int q0 = blockIdx.x*128 + w*16;
  const size_t rowbase = (size_t)b*1024;

  bf16x8 aq;
  {
    const float qscale = 0.17677669529663687f;
    const uint16_t* p = qkv + ((rowbase + q0 + r)*768 + h*32 + q*8);
    bf16x8 t = *(const bf16x8*)p;
#pragma unroll
    for (int j=0;j<8;++j)
      t[j] = (short)f2bf(bf2f((uint16_t)t[j]) * qscale);
    aq = t;
  }

  f32x4 o[2];
  o[0]=(f32x4){0.f,0.f,0.f,0.f}; o[1]=(f32x4){0.f,0.f,0.f,0.f};
  float l = 0.f;

  for (int c=0;c<4;++c){
    __syncthreads();
    if (tid < 256) stage_K(Kl, qkv, rowbase, c, h, tid);
    else           stage_V(VT, qkv, rowbase, c, h, tid-256);
    __syncthreads();
#pragma unroll 2
    for (int s32=0; s32<8; ++s32){
#pragma unroll
      for (int t2=0;t2<2;++t2){
        int rn = s32*32 + t2*16 + r;
        int sz = (rn&3) ^ ((rn>>2)&1);
        bf16x8 bk = *(const bf16x8*)&Kl[rn*32 + ((q ^ sz))*8];
        f32x4 z = (f32x4){0.f,0.f,0.f,0.f};
        f32x4 st = __builtin_amdgcn_mfma_f32_16x16x32_bf16(bk, aq, z, 0,0,0);
        union{uint16_t u[4]; uint64_t q64;} pk;
#pragma unroll
        for (int reg=0;reg<4;++reg){
          float p = __expf(st[reg]);
          l += p;
          pk.u[reg] = f2bf(p);
        }
        *(uint64_t*)&Pl[w][r*36 + t2*16 + q*4] = pk.q64;
      }
      bf16x8 bv[2];
#pragma unroll
      for (int db=0;db<2;++db){
        int dh = db*16 + r;
        bv[db] = *(const bf16x8*)&VT[dh*256 + (((s32*4 + q) ^ (dh&7)))*8];
      }
      bf16x8 ap = *(const bf16x8*)&Pl[w][r*36 + q*8];
#pragma unroll
      for (int db=0;db<2;++db)
        o[db] = __builtin_amdgcn_mfma_f32_16x16x32_bf16(ap, bv[db], o[db], 0,0,0);
    }
  }

  l += __shfl_xor(l, 16);
  l += __shfl_xor(l, 32);
#pragma unroll
  for (int db=0;db<2;++db)
#pragma unroll
    for (int reg=0;reg<4;++reg){
      float li = __shfl(l, q*4 + reg);
      int qr = q0 + q*4 + reg;
      O[(rowbase + qr)*256 + h*32 + db*16 + r] = f2bf(o[db][reg] / li);
    }
}

// ===========================================================================
extern "C" void kernel_launch(void* const* d_in, const int* in_sizes, int n_in,
                              void* d_out, int out_size, void* d_ws, size_t ws_size,
                              hipStream_t stream){
  const float* features = (const float*)d_in[0];
  const float* inc      = (const float*)d_in[1];
  const float* vc_Win   = (const float*)d_in[2];
  const float* vc_bin   = (const float*)d_in[3];
  const float* vc_Wout  = (const float*)d_in[4];
  const float* vc_bout  = (const float*)d_in[5];
  const float* vc_Wproj = (const float*)d_in[6];
  const float* vc_ln_g  = (const float*)d_in[7];
  const float* vc_ln_b  = (const float*)d_in[8];
  const float* vc_alpha = (const float*)d_in[9];
  const float* ec_Wproj = (const float*)d_in[14];
  const float* ec_ln_g  = (const float*)d_in[15];
  const float* ec_ln_b  = (const float*)d_in[16];
  const float* ec_alpha = (const float*)d_in[17];

  float* out = (float*)d_out;
  float* out_node = out;                 // [8,1024,256]
  float* out_edge = out + 2097152;       // [8,1536,256]
  float* out_inc  = out + 5242880;       // [8,1024,1536]

  char* ws = (char*)d_ws;
  uint16_t* XB     = (uint16_t*)(ws + 0);          // 4,194,304 (dead after qkv)
  float*    PART   = (float*)   (ws + 0);          // alias: 98,304 (8*12*256)
  uint16_t* WINB   = (uint16_t*)(ws + 4194304);    // 393,216
  uint16_t* WOUTB  = (uint16_t*)(ws + 4587520);    // 131,072
  uint16_t* WPVB   = (uint16_t*)(ws + 4718592);    // 131,072
  uint16_t* WPEB   = (uint16_t*)(ws + 4849664);    // 131,072
  uint16_t* INCB   = (uint16_t*)(ws + 4988928);    // 25,165,824
  uint16_t* INCT   = (uint16_t*)(ws + 30154752);   // 25,165,824
  uint16_t* QKVB   = (uint16_t*)(ws + 55320576);   // 12,582,912
  uint16_t* SCORESB= (uint16_t*)(ws + 55320576);   // alias: QKVB dead after attn
  uint16_t* OB     = (uint16_t*)(ws + 67903488);   // 4,194,304
  uint16_t* ATTNT  = (uint16_t*)(ws + 72097792);   // 4,194,304
  uint16_t* BASET  = (uint16_t*)(ws + 82583552);   // 6,291,456
  uint16_t* W0B    = (uint16_t*)(ws + 88875008);   // 4,194,304  (~93 MB)

  // prep: inc (f32 out + bf16 + bf16^T) and all f32->bf16 casts, one kernel
  prep<<<14720,256,0,stream>>>(inc, out_inc, INCB, INCT,
                               features, vc_Win, vc_Wout, vc_Wproj, ec_Wproj,
                               XB, WINB, WOUTB, WPVB, WPEB);

  // MHA(features): qkv -> attention -> out-proj (writes ATTNT transposed)
  gemm_nt<4,64,0><<<dim3(64,6,1),256,0,stream>>>(XB, WINB, nullptr, QKVB, vc_bin,
                                                 8192,768,256, 0,0,0, nullptr);
  attn_fwd<<<dim3(8,64),512,0,stream>>>(QKVB, OB);
  gemm_nt<4,64,1><<<dim3(64,2,1),256,0,stream>>>(OB, WOUTB, nullptr, ATTNT, vc_bout,
                                                 8192,256,256, 0,0,0, nullptr);

  // scores = inc^T @ attn -> bf16, with per-block column exp-sum partials
  gemm_nt<4,64,2><<<dim3(12,2,8),256,0,stream>>>(INCT, ATTNT, nullptr, SCORESB, nullptr,
                                                 1536,256,1024,
                                                 1536L*1024, 256L*1024, 1536L*256, PART);

  // edge path fully fused: PART->1/L, p=v*exp(v)/L staging, GEMM, LN,
  // out_edge f32 + BASET bf16 transposed
  gemm_ln_edge<<<192,512,0,stream>>>(SCORESB, WPVB, PART, vc_ln_g, vc_ln_b,
                                     vc_alpha, out_edge, BASET);

  // node path: W0 = inc @ base (128-row tiles), project + fused LN/blend
  gemm_nt<4,64,0><<<dim3(8,2,8),256,0,stream>>>(INCB, BASET, nullptr, W0B, nullptr,
                                                1024,256,1536,
                                                1024L*1536, 256L*1536, 1024L*256, nullptr);
  gemm_ln_node<<<128,512,0,stream>>>(W0B, WPEB, ec_ln_g, ec_ln_b, ec_alpha,
                                     features, out_node);
}

// Round 8
// 264.255 us; speedup vs baseline: 1.0796x; 1.0796x over previous
//
#include <hip/hip_runtime.h>
#include <stdint.h>

// ============================================================================
// MessagePassing collapse:
//   e2 = (3+a_vc)*base,  base = LN((scores*softmax_e(scores)) @ Wp_vc^T)
//   n2 = (1+a)^3 * features + (1-a)((1+a)^2+(1+a)+1) * nb,  a = ec_alpha
//   nb = LN((inc @ base) @ Wp_ec^T)  (LN positive-scale-invariant)
//   EC's MHA is dead code.
// R8: REVERT to R6 (264.9 µs known-good). R7's WM=4 tiles shrank GEMM grids
// below 256 blocks (machine under-filled) -> +20 µs. Lesson: at these shapes,
// grid >= 256 blocks beats per-block MFMA amortization.
// ============================================================================

#define DEV static __device__ __forceinline__

typedef __attribute__((ext_vector_type(8))) short bf16x8;
typedef __attribute__((ext_vector_type(4))) float f32x4;

DEV uint16_t f2bf(float x){
  union{float f; uint32_t u;} v; v.f=x;
  uint32_t r = v.u + 0x7fffu + ((v.u>>16)&1u);
  return (uint16_t)(r>>16);
}
DEV float bf2f(uint16_t b){
  union{uint32_t u; float f;} v; v.u=((uint32_t)b)<<16; return v.f;
}

#if __has_builtin(__builtin_amdgcn_global_load_lds)
#define HAVE_GLL 1
#else
#define HAVE_GLL 0
#endif

DEV void load_lds16(const uint16_t* g, void* l){
#if HAVE_GLL
  __builtin_amdgcn_global_load_lds((const __attribute__((address_space(1))) uint32_t*)g,
                                   (__attribute__((address_space(3))) uint32_t*)l, 16, 0, 0);
#else
  *(bf16x8*)l = *(const bf16x8*)g;
#endif
}

// ---------------------------------------------------------------------------
// merged prep: blocks [0,12288) = inc prep (f32 copy out + bf16 + bf16^T);
// blocks [12288,14720) = f32->bf16 casts of features + 4 weights.
// ---------------------------------------------------------------------------
__global__ __launch_bounds__(256)
void prep(const float* __restrict__ inc, float* __restrict__ out_inc,
          uint16_t* __restrict__ incb, uint16_t* __restrict__ incT,
          const float* __restrict__ feats, const float* __restrict__ win,
          const float* __restrict__ wout, const float* __restrict__ wpv,
          const float* __restrict__ wpe,
          uint16_t* __restrict__ xb, uint16_t* __restrict__ ow,
          uint16_t* __restrict__ oo, uint16_t* __restrict__ ov,
          uint16_t* __restrict__ oe){
  __shared__ float T[32][33];
  int bx = blockIdx.x;
  int tid = threadIdx.x;
  if (bx < 12288){
    int x = bx % 48;           // e tile
    int t = bx / 48;
    int y = t % 32;            // m tile
    int b = t / 32;            // batch
    int c0 = x*32, r0 = y*32;
    int tx = tid & 31, ty = tid >> 5;
    size_t base = (size_t)b*1024*1536;
#pragma unroll
    for (int j=0;j<4;++j){
      int r = r0 + ty + j*8;
      size_t idx = base + (size_t)r*1536 + c0 + tx;
      float v = inc[idx];
      T[ty+j*8][tx] = v;
      out_inc[idx] = v;
      incb[idx] = f2bf(v);
    }
    __syncthreads();
    size_t baseT = (size_t)b*1536*1024;
#pragma unroll
    for (int j=0;j<4;++j){
      int c = c0 + ty + j*8;
      incT[baseT + (size_t)c*1024 + r0 + tx] = f2bf(T[tx][ty+j*8]);
    }
  } else {
    int i = (bx - 12288)*256 + tid;   // i4 units, total 622592
    const float* src; uint16_t* dst; int j;
    if (i < 524288){ src=feats; dst=xb; j=i; }
    else {
      i -= 524288;
      if (i < 49152){ src=win; dst=ow; j=i; }
      else if (i < 65536){ src=wout; dst=oo; j=i-49152; }
      else if (i < 81920){ src=wpv; dst=ov; j=i-65536; }
      else { src=wpe; dst=oe; j=i-81920; }
    }
    float4 v = ((const float4*)src)[j];
    union { uint16_t u[4]; uint64_t q; } p;
    p.u[0]=f2bf(v.x); p.u[1]=f2bf(v.y); p.u[2]=f2bf(v.z); p.u[3]=f2bf(v.w);
    ((uint64_t*)dst)[j] = p.q;
  }
}

// ---------------------------------------------------------------------------
// NT bf16 GEMM: C[M,N] = A[M,K] * B[N,K]^T (+bias).
// WM: rows/wave = WM*16, M-tile = WM*32. N-tile 128. 256 thr (2x2 waves).
// EPI: 0 = plain (Cf f32 / Cb bf16 row-major)
//      1 = transposed bf16 store (per-batch [N][1024] from flat M=8*1024)
//      2 = row-major store + per-block column exp-sum partials (write-only)
// ---------------------------------------------------------------------------
template<int WM, int BK, int EPI>
__global__ __launch_bounds__(256, 3)
void gemm_nt(const uint16_t* __restrict__ A, const uint16_t* __restrict__ B,
             float* __restrict__ Cf, uint16_t* __restrict__ Cb,
             const float* __restrict__ bias,
             int M, int N, int K, long sA, long sB, long sC,
             float* __restrict__ extra){
  constexpr int AROWS = WM*32;
  constexpr int UPR = BK/8;        // 16B units per row
  constexpr int RPP = 256/UPR;     // rows staged per pass
  __shared__ short As[AROWS*BK];
  __shared__ short Bs[128*BK];
  const int tid = threadIdx.x;
  const int lane = tid & 63;
  const int w = tid >> 6;
  const int wm = w & 1, wn = w >> 1;
  const int r = lane & 15, q = lane >> 4;
  const long zb = blockIdx.z;
  const uint16_t* Ab = A + zb*sA + (size_t)(blockIdx.x*AROWS)*K;
  const uint16_t* Bb = B + zb*sB + (size_t)(blockIdx.y*128)*K;
  f32x4 acc[WM][4];
#pragma unroll
  for (int i=0;i<WM;++i)
#pragma unroll
    for (int j=0;j<4;++j) acc[i][j] = (f32x4){0.f,0.f,0.f,0.f};

  const int srow = tid / UPR;
  const int sblk = tid % UPR;

  for (int kb = 0; kb < K; kb += BK){
#pragma unroll
    for (int i=0;i<AROWS/RPP;++i){
      int row = srow + RPP*i;
      int lblk = sblk ^ (row & (UPR-1));
      load_lds16(Ab + (size_t)row*K + kb + lblk*8, (char*)As + i*4096 + tid*16);
    }
#pragma unroll
    for (int i=0;i<128/RPP;++i){
      int row = srow + RPP*i;
      int lblk = sblk ^ (row & (UPR-1));
      load_lds16(Bb + (size_t)row*K + kb + lblk*8, (char*)Bs + i*4096 + tid*16);
    }
    __syncthreads();
#pragma unroll
    for (int kc=0;kc<BK/32;++kc){
      bf16x8 af[WM], bf[4];
#pragma unroll
      for (int mt=0;mt<WM;++mt){
        int m = wm*(WM*16) + mt*16 + r;
        af[mt] = *(const bf16x8*)&As[m*BK + ((kc*4 + q) ^ (m&(UPR-1)))*8];
      }
#pragma unroll
      for (int nt=0;nt<4;++nt){
        int n = wn*64 + nt*16 + r;
        bf[nt] = *(const bf16x8*)&Bs[n*BK + ((kc*4 + q) ^ (n&(UPR-1)))*8];
      }
#pragma unroll
      for (int mt=0;mt<WM;++mt)
#pragma unroll
        for (int nt=0;nt<4;++nt)
          acc[mt][nt] = __builtin_amdgcn_mfma_f32_16x16x32_bf16(af[mt], bf[nt], acc[mt][nt], 0,0,0);
    }
    __syncthreads();
  }

  const int gm0 = blockIdx.x*AROWS + wm*(WM*16);
  const int gn0 = blockIdx.y*128 + wn*64;

  if constexpr (EPI == 1){
    // transposed bf16: out[b][gn][m'] with b = gm>>10, m' = gm&1023
#pragma unroll
    for (int mt=0;mt<WM;++mt){
      int gmb = gm0 + mt*16 + q*4;           // 4 consecutive rows via reg
      size_t bb_ = (size_t)(gmb>>10)*(256*1024);
      int mm = gmb & 1023;
#pragma unroll
      for (int nt=0;nt<4;++nt){
        int gn = gn0 + nt*16 + r;
        float bv = bias ? bias[gn] : 0.f;
        union{uint16_t u[4]; uint64_t q64;} pk;
#pragma unroll
        for (int reg=0;reg<4;++reg) pk.u[reg] = f2bf(acc[mt][nt][reg] + bv);
        *(uint64_t*)(Cb + bb_ + (size_t)gn*1024 + mm) = pk.q64;
      }
    }
  } else {
#pragma unroll
    for (int mt=0;mt<WM;++mt){
#pragma unroll
      for (int nt=0;nt<4;++nt){
        int gn = gn0 + nt*16 + r;
        float bv = bias ? bias[gn] : 0.f;
#pragma unroll
        for (int reg=0;reg<4;++reg){
          int gm = gm0 + mt*16 + q*4 + reg;   // C/D: col=lane&15, row=quad*4+reg
          float v = acc[mt][nt][reg] + bv;
          size_t off = (size_t)(zb*sC) + (size_t)gm*N + gn;
          if (Cf) Cf[off] = v;
          if (Cb) Cb[off] = f2bf(v);
        }
      }
    }
    if constexpr (EPI == 2){
      // per-block column sums of exp(score) -> extra[(zb*gridDim.x+bx)*256+gn]
      __shared__ float colsum[2][128];
#pragma unroll
      for (int nt=0;nt<4;++nt){
        float s = 0.f;
#pragma unroll
        for (int mt=0;mt<WM;++mt)
#pragma unroll
          for (int reg=0;reg<4;++reg) s += __expf(acc[mt][nt][reg]);
        s += __shfl_xor(s, 16);
        s += __shfl_xor(s, 32);
        if (q == 0) colsum[wm][wn*64 + nt*16 + r] = s;
      }
      __syncthreads();
      if (tid < 128){
        float v = colsum[0][tid] + colsum[1][tid];
        extra[((size_t)zb*gridDim.x + blockIdx.x)*256 + blockIdx.y*128 + tid] = v;
      }
    }
  }
}

// ---------------------------------------------------------------------------
// Edge path: A = p(scores) with p = v*exp(v)/L computed during staging;
// L folded from PART (24 partials/batch) in-kernel. GEMM vs Wpv^T + LN.
// Tile 64m x 256n, BK=64, 512 thr. Writes out_edge f32 + BASET bf16 [b][d][e].
// ---------------------------------------------------------------------------
__global__ __launch_bounds__(512, 4)
void gemm_ln_edge(const uint16_t* __restrict__ SB, const uint16_t* __restrict__ B,
                  const float* __restrict__ part, const float* __restrict__ g,
                  const float* __restrict__ bb, const float* __restrict__ alpha,
                  float* __restrict__ out, uint16_t* __restrict__ baset){
  __shared__ short As[64*64];
  __shared__ short Bs[256*64];
  __shared__ float lnS[4][64], lnQ[4][64];
  __shared__ float PLinv[256];
  __shared__ float Phalf[2][256];
  const int tid = threadIdx.x;
  const int lane = tid & 63;
  const int w = tid >> 6;
  const int wm = w & 1;
  const int wn2 = w >> 1;
  const int r = lane & 15, q = lane >> 4;
  const int batch = blockIdx.x / 24;

  // fold 24 PART partials -> 1/L (in LDS)
  {
    int d = tid & 255, h = tid >> 8;
    float s = 0.f;
#pragma unroll
    for (int i=0;i<12;++i) s += part[((size_t)batch*24 + h*12 + i)*256 + d];
    Phalf[h][d] = s;
  }
  __syncthreads();
  if (tid < 256) PLinv[tid] = 1.0f / (Phalf[0][tid] + Phalf[1][tid]);
  __syncthreads();

  f32x4 acc[2][4];
#pragma unroll
  for (int i=0;i<2;++i)
#pragma unroll
    for (int j=0;j<4;++j) acc[i][j] = (f32x4){0.f,0.f,0.f,0.f};

  const int srow = tid >> 3;   // 0..63
  const int sblk = tid & 7;

  for (int kb = 0; kb < 256; kb += 64){
    // A stage with softmax-apply transform (VGPR path)
    {
      bf16x8 v = *(const bf16x8*)(SB + (size_t)(blockIdx.x*64 + srow)*256 + kb + sblk*8);
      const float* Lp = &PLinv[kb + sblk*8];
      bf16x8 pv;
#pragma unroll
      for (int j=0;j<8;++j){
        float x = bf2f((uint16_t)v[j]);
        pv[j] = (short)f2bf(x * __expf(x) * Lp[j]);
      }
      *(bf16x8*)&As[srow*64 + (sblk ^ (srow&7))*8] = pv;
    }
#pragma unroll
    for (int i=0;i<4;++i){
      int row = srow + 64*i;
      int lblk = sblk ^ (row & 7);
      load_lds16(B + (size_t)row*256 + kb + lblk*8, (char*)Bs + i*8192 + tid*16);
    }
    __syncthreads();
#pragma unroll
    for (int kc=0;kc<2;++kc){
      bf16x8 af[2], bf[4];
#pragma unroll
      for (int mt=0;mt<2;++mt){
        int m = wm*32 + mt*16 + r;
        af[mt] = *(const bf16x8*)&As[m*64 + ((kc*4 + q) ^ (m&7))*8];
      }
#pragma unroll
      for (int nt=0;nt<4;++nt){
        int n = wn2*64 + nt*16 + r;
        bf[nt] = *(const bf16x8*)&Bs[n*64 + ((kc*4 + q) ^ (n&7))*8];
      }
#pragma unroll
      for (int mt=0;mt<2;++mt)
#pragma unroll
        for (int nt=0;nt<4;++nt)
          acc[mt][nt] = __builtin_amdgcn_mfma_f32_16x16x32_bf16(af[mt], bf[nt], acc[mt][nt], 0,0,0);
    }
    __syncthreads();
  }

  // cross-wave LN reduction
  float rs[2][4], rq[2][4];
#pragma unroll
  for (int mt=0;mt<2;++mt)
#pragma unroll
    for (int reg=0;reg<4;++reg){
      float s=0.f, s2=0.f;
#pragma unroll
      for (int nt=0;nt<4;++nt){
        float v = acc[mt][nt][reg];
        s += v; s2 += v*v;
      }
#pragma unroll
      for (int off=1; off<16; off<<=1){ s += __shfl_xor(s,off); s2 += __shfl_xor(s2,off); }
      rs[mt][reg]=s; rq[mt][reg]=s2;
    }
  if (r == 0){
#pragma unroll
    for (int mt=0;mt<2;++mt)
#pragma unroll
      for (int reg=0;reg<4;++reg){
        int row = wm*32 + mt*16 + q*4 + reg;
        lnS[wn2][row] = rs[mt][reg];
        lnQ[wn2][row] = rq[mt][reg];
      }
  }
  __syncthreads();

  const float c0 = 3.0f + alpha[0];
  float mu_[2][4], rstd_[2][4];
#pragma unroll
  for (int mt=0;mt<2;++mt)
#pragma unroll
    for (int reg=0;reg<4;++reg){
      int row = wm*32 + mt*16 + q*4 + reg;
      float S = lnS[0][row]+lnS[1][row]+lnS[2][row]+lnS[3][row];
      float Q = lnQ[0][row]+lnQ[1][row]+lnQ[2][row]+lnQ[3][row];
      float mu = S * (1.f/256.f);
      float var = fmaxf(Q*(1.f/256.f) - mu*mu, 0.f);
      mu_[mt][reg] = mu;
      rstd_[mt][reg] = rsqrtf(var + 1e-5f);
    }

  int e0 = (blockIdx.x % 24) * 64 + wm*32;
#pragma unroll
  for (int mt=0;mt<2;++mt){
#pragma unroll
    for (int nt=0;nt<4;++nt){
      int gn = wn2*64 + nt*16 + r;
      float gv = g[gn], bv = bb[gn];
      union{uint16_t u[4]; uint64_t q64;} pk;
#pragma unroll
      for (int reg=0;reg<4;++reg){
        int row = wm*32 + mt*16 + q*4 + reg;
        size_t gm = (size_t)blockIdx.x*64 + row;
        float o = ((acc[mt][nt][reg]-mu_[mt][reg])*rstd_[mt][reg]*gv + bv) * c0;
        pk.u[reg] = f2bf(o);
        out[gm*256 + gn] = o;
      }
      int ee = e0 + mt*16 + q*4;
      *(uint64_t*)(baset + ((size_t)batch*256 + gn)*1536 + ee) = pk.q64;
    }
  }
}

// ---------------------------------------------------------------------------
// GEMM + LN/blend (node path): out = cf*feat + cn*LN(A@B^T). 64x256, K=256.
// ---------------------------------------------------------------------------
__global__ __launch_bounds__(512, 4)
void gemm_ln_node(const uint16_t* __restrict__ A, const uint16_t* __restrict__ B,
                  const float* __restrict__ g, const float* __restrict__ bb,
                  const float* __restrict__ alpha, const float* __restrict__ feats,
                  float* __restrict__ out){
  __shared__ short As[64*64];
  __shared__ short Bs[256*64];
  __shared__ float lnS[4][64], lnQ[4][64];
  const int tid = threadIdx.x;
  const int lane = tid & 63;
  const int w = tid >> 6;
  const int wm = w & 1;
  const int wn2 = w >> 1;
  const int r = lane & 15, q = lane >> 4;
  const uint16_t* Ab = A + (size_t)(blockIdx.x*64)*256;
  f32x4 acc[2][4];
#pragma unroll
  for (int i=0;i<2;++i)
#pragma unroll
    for (int j=0;j<4;++j) acc[i][j] = (f32x4){0.f,0.f,0.f,0.f};

  const int srow = tid >> 3;
  const int sblk = tid & 7;

  for (int kb = 0; kb < 256; kb += 64){
    {
      int lblk = sblk ^ (srow & 7);
      load_lds16(Ab + (size_t)srow*256 + kb + lblk*8, (char*)As + tid*16);
    }
#pragma unroll
    for (int i=0;i<4;++i){
      int row = srow + 64*i;
      int lblk = sblk ^ (row & 7);
      load_lds16(B + (size_t)row*256 + kb + lblk*8, (char*)Bs + i*8192 + tid*16);
    }
    __syncthreads();
#pragma unroll
    for (int kc=0;kc<2;++kc){
      bf16x8 af[2], bf[4];
#pragma unroll
      for (int mt=0;mt<2;++mt){
        int m = wm*32 + mt*16 + r;
        af[mt] = *(const bf16x8*)&As[m*64 + ((kc*4 + q) ^ (m&7))*8];
      }
#pragma unroll
      for (int nt=0;nt<4;++nt){
        int n = wn2*64 + nt*16 + r;
        bf[nt] = *(const bf16x8*)&Bs[n*64 + ((kc*4 + q) ^ (n&7))*8];
      }
#pragma unroll
      for (int mt=0;mt<2;++mt)
#pragma unroll
        for (int nt=0;nt<4;++nt)
          acc[mt][nt] = __builtin_amdgcn_mfma_f32_16x16x32_bf16(af[mt], bf[nt], acc[mt][nt], 0,0,0);
    }
    __syncthreads();
  }

  float rs[2][4], rq[2][4];
#pragma unroll
  for (int mt=0;mt<2;++mt)
#pragma unroll
    for (int reg=0;reg<4;++reg){
      float s=0.f, s2=0.f;
#pragma unroll
      for (int nt=0;nt<4;++nt){
        float v = acc[mt][nt][reg];
        s += v; s2 += v*v;
      }
#pragma unroll
      for (int off=1; off<16; off<<=1){ s += __shfl_xor(s,off); s2 += __shfl_xor(s2,off); }
      rs[mt][reg]=s; rq[mt][reg]=s2;
    }
  if (r == 0){
#pragma unroll
    for (int mt=0;mt<2;++mt)
#pragma unroll
      for (int reg=0;reg<4;++reg){
        int row = wm*32 + mt*16 + q*4 + reg;
        lnS[wn2][row] = rs[mt][reg];
        lnQ[wn2][row] = rq[mt][reg];
      }
  }
  __syncthreads();

  const float a = alpha[0];
  const float ap1 = 1.f + a;
  const float cn = (1.f - a)*(ap1*ap1 + ap1 + 1.f);
  const float cf = ap1*ap1*ap1;

#pragma unroll
  for (int mt=0;mt<2;++mt){
#pragma unroll
    for (int reg=0;reg<4;++reg){
      int row = wm*32 + mt*16 + q*4 + reg;
      float S = lnS[0][row]+lnS[1][row]+lnS[2][row]+lnS[3][row];
      float Q = lnQ[0][row]+lnQ[1][row]+lnQ[2][row]+lnQ[3][row];
      float mu = S * (1.f/256.f);
      float var = fmaxf(Q*(1.f/256.f) - mu*mu, 0.f);
      float rstd = rsqrtf(var + 1e-5f);
      size_t gm = (size_t)blockIdx.x*64 + row;
#pragma unroll
      for (int nt=0;nt<4;++nt){
        int gn = wn2*64 + nt*16 + r;
        float nv = (acc[mt][nt][reg]-mu)*rstd*g[gn] + bb[gn];
        out[gm*256 + gn] = cf*feats[gm*256+gn] + cn*nv;
      }
    }
  }
}

// ---------------------------------------------------------------------------
// Attention: S^T = K*Q^T (A/B frags interchangeable), packed b64 P-store,
// scalar l. 512 thr = 8 waves x 16 q-rows. grid (8, 64). Max-free softmax.
// ---------------------------------------------------------------------------
DEV void stage_K(short* Kl, const uint16_t* __restrict__ qkv, size_t rowbase,
                 int c, int h, int kr){
  const uint16_t* kp = qkv + ((rowbase + c*256 + kr)*768 + 256 + h*32);
  int sz = (kr&3) ^ ((kr>>2)&1);
#pragma unroll
  for (int lb=0; lb<4; ++lb){
    bf16x8 v = *(const bf16x8*)(kp + lb*8);
    *(bf16x8*)&Kl[kr*32 + ((lb ^ sz))*8] = v;
  }
}

DEV void stage_V(short* VT, const uint16_t* __restrict__ qkv, size_t rowbase,
                 int c, int h, int t){
  int kvp = (t>>1)*2;
  int dhh = (t&1)*16;
  const uint16_t* v0 = qkv + ((rowbase + c*256 + kvp)*768 + 512 + h*32 + dhh);
  const uint16_t* v1 = v0 + 768;
  bf16x8 a0 = *(const bf16x8*)(v0);
  bf16x8 a1 = *(const bf16x8*)(v0+8);
  bf16x8 b0 = *(const bf16x8*)(v1);
  bf16x8 b1 = *(const bf16x8*)(v1+8);
  int blkbase = kvp>>3, off = kvp&7;
#pragma unroll
  for (int i=0;i<8;++i){
    int dh = dhh + i;
    uint32_t pack = (uint32_t)(uint16_t)a0[i] | ((uint32_t)(uint16_t)b0[i]<<16);
    *(uint32_t*)&VT[dh*256 + ((blkbase ^ (dh&7))*8) + off] = pack;
  }
#pragma unroll
  for (int i=0;i<8;++i){
    int dh = dhh + 8 + i;
    uint32_t pack = (uint32_t)(uint16_t)a1[i] | ((uint32_t)(uint16_t)b1[i]<<16);
    *(uint32_t*)&VT[dh*256 + ((blkbase ^ (dh&7))*8) + off] = pack;
  }
}

__global__ __launch_bounds__(512)
void attn_fwd(const uint16_t* __restrict__ qkv, uint16_t* __restrict__ O){
  __shared__ short Kl[256*32];
  __shared__ short VT[32*256];
  __shared__ short Pl[8][16*36];
  const int tid = threadIdx.x, lane = tid&63, w = tid>>6;
  const int r = lane&15, q = lane>>4;
  const int bh = blockIdx.y, b = bh>>3, h = bh&7;
  const int q0 = blockIdx.x*128 + w*16;
  const size_t rowbase = (size_t)b*1024;

  bf16x8 aq;
  {
    const float qscale = 0.17677669529663687f;
    const uint16_t* p = qkv + ((rowbase + q0 + r)*768 + h*32 + q*8);
    bf16x8 t = *(const bf16x8*)p;
#pragma unroll
    for (int j=0;j<8;++j)
      t[j] = (short)f2bf(bf2f((uint16_t)t[j]) * qscale);
    aq = t;
  }

  f32x4 o[2];
  o[0]=(f32x4){0.f,0.f,0.f,0.f}; o[1]=(f32x4){0.f,0.f,0.f,0.f};
  float l = 0.f;

  for (int c=0;c<4;++c){
    __syncthreads();
    if (tid < 256) stage_K(Kl, qkv, rowbase, c, h, tid);
    else           stage_V(VT, qkv, rowbase, c, h, tid-256);
    __syncthreads();
    for (int s32=0; s32<8; ++s32){
#pragma unroll
      for (int t2=0;t2<2;++t2){
        int rn = s32*32 + t2*16 + r;
        int sz = (rn&3) ^ ((rn>>2)&1);
        bf16x8 bk = *(const bf16x8*)&Kl[rn*32 + ((q ^ sz))*8];
        f32x4 z = (f32x4){0.f,0.f,0.f,0.f};
        f32x4 st = __builtin_amdgcn_mfma_f32_16x16x32_bf16(bk, aq, z, 0,0,0);
        union{uint16_t u[4]; uint64_t q64;} pk;
#pragma unroll
        for (int reg=0;reg<4;++reg){
          float p = __expf(st[reg]);
          l += p;
          pk.u[reg] = f2bf(p);
        }
        *(uint64_t*)&Pl[w][r*36 + t2*16 + q*4] = pk.q64;
      }
      bf16x8 bv[2];
#pragma unroll
      for (int db=0;db<2;++db){
        int dh = db*16 + r;
        bv[db] = *(const bf16x8*)&VT[dh*256 + (((s32*4 + q) ^ (dh&7)))*8];
      }
      bf16x8 ap = *(const bf16x8*)&Pl[w][r*36 + q*8];
#pragma unroll
      for (int db=0;db<2;++db)
        o[db] = __builtin_amdgcn_mfma_f32_16x16x32_bf16(ap, bv[db], o[db], 0,0,0);
    }
  }

  l += __shfl_xor(l, 16);
  l += __shfl_xor(l, 32);
#pragma unroll
  for (int db=0;db<2;++db)
#pragma unroll
    for (int reg=0;reg<4;++reg){
      float li = __shfl(l, q*4 + reg);
      int qr = q0 + q*4 + reg;
      O[(rowbase + qr)*256 + h*32 + db*16 + r] = f2bf(o[db][reg] / li);
    }
}

// ===========================================================================
extern "C" void kernel_launch(void* const* d_in, const int* in_sizes, int n_in,
                              void* d_out, int out_size, void* d_ws, size_t ws_size,
                              hipStream_t stream){
  const float* features = (const float*)d_in[0];
  const float* inc      = (const float*)d_in[1];
  const float* vc_Win   = (const float*)d_in[2];
  const float* vc_bin   = (const float*)d_in[3];
  const float* vc_Wout  = (const float*)d_in[4];
  const float* vc_bout  = (const float*)d_in[5];
  const float* vc_Wproj = (const float*)d_in[6];
  const float* vc_ln_g  = (const float*)d_in[7];
  const float* vc_ln_b  = (const float*)d_in[8];
  const float* vc_alpha = (const float*)d_in[9];
  const float* ec_Wproj = (const float*)d_in[14];
  const float* ec_ln_g  = (const float*)d_in[15];
  const float* ec_ln_b  = (const float*)d_in[16];
  const float* ec_alpha = (const float*)d_in[17];

  float* out = (float*)d_out;
  float* out_node = out;                 // [8,1024,256]
  float* out_edge = out + 2097152;       // [8,1536,256]
  float* out_inc  = out + 5242880;       // [8,1024,1536]

  char* ws = (char*)d_ws;
  uint16_t* XB     = (uint16_t*)(ws + 0);          // 4,194,304 (dead after qkv)
  float*    PART   = (float*)   (ws + 0);          // alias: 196,608 (8*24*256)
  uint16_t* WINB   = (uint16_t*)(ws + 4194304);    // 393,216
  uint16_t* WOUTB  = (uint16_t*)(ws + 4587520);    // 131,072
  uint16_t* WPVB   = (uint16_t*)(ws + 4718592);    // 131,072
  uint16_t* WPEB   = (uint16_t*)(ws + 4849664);    // 131,072
  uint16_t* INCB   = (uint16_t*)(ws + 4988928);    // 25,165,824
  uint16_t* INCT   = (uint16_t*)(ws + 30154752);   // 25,165,824
  uint16_t* QKVB   = (uint16_t*)(ws + 55320576);   // 12,582,912
  uint16_t* SCORESB= (uint16_t*)(ws + 55320576);   // alias: QKVB dead after attn
  uint16_t* OB     = (uint16_t*)(ws + 67903488);   // 4,194,304
  uint16_t* ATTNT  = (uint16_t*)(ws + 72097792);   // 4,194,304
  uint16_t* BASET  = (uint16_t*)(ws + 82583552);   // 6,291,456
  uint16_t* W0B    = (uint16_t*)(ws + 88875008);   // 4,194,304  (~93 MB)

  // prep: inc (f32 out + bf16 + bf16^T) and all f32->bf16 casts, one kernel
  prep<<<14720,256,0,stream>>>(inc, out_inc, INCB, INCT,
                               features, vc_Win, vc_Wout, vc_Wproj, ec_Wproj,
                               XB, WINB, WOUTB, WPVB, WPEB);

  // MHA(features): qkv -> attention -> out-proj (writes ATTNT transposed)
  gemm_nt<4,64,0><<<dim3(64,6,1),256,0,stream>>>(XB, WINB, nullptr, QKVB, vc_bin,
                                                 8192,768,256, 0,0,0, nullptr);
  attn_fwd<<<dim3(8,64),512,0,stream>>>(QKVB, OB);
  gemm_nt<2,128,1><<<dim3(128,2,1),256,0,stream>>>(OB, WOUTB, nullptr, ATTNT, vc_bout,
                                                   8192,256,256, 0,0,0, nullptr);

  // scores = inc^T @ attn -> bf16, with per-block column exp-sum partials
  gemm_nt<2,128,2><<<dim3(24,2,8),256,0,stream>>>(INCT, ATTNT, nullptr, SCORESB, nullptr,
                                                  1536,256,1024,
                                                  1536L*1024, 256L*1024, 1536L*256, PART);

  // edge path fully fused: PART->1/L, p=v*exp(v)/L staging, GEMM, LN,
  // out_edge f32 + BASET bf16 transposed
  gemm_ln_edge<<<192,512,0,stream>>>(SCORESB, WPVB, PART, vc_ln_g, vc_ln_b,
                                     vc_alpha, out_edge, BASET);

  // node path: W0 = inc @ base, project + fused LN/blend
  gemm_nt<2,128,0><<<dim3(16,2,8),256,0,stream>>>(INCB, BASET, nullptr, W0B, nullptr,
                                                  1024,256,1536,
                                                  1024L*1536, 256L*1536, 1024L*256, nullptr);
  gemm_ln_node<<<128,512,0,stream>>>(W0B, WPEB, ec_ln_g, ec_ln_b, ec_alpha,
                                     features, out_node);
}

// Round 9
// 260.524 us; speedup vs baseline: 1.0951x; 1.0143x over previous
//
#include <hip/hip_runtime.h>
#include <stdint.h>

// ============================================================================
// MessagePassing collapse:
//   e2 = (3+a_vc)*base,  base = LN((scores*softmax_e(scores)) @ Wp_vc^T)
//   n2 = (1+a)^3 * features + (1-a)((1+a)^2+(1+a)+1) * nb,  a = ec_alpha
//   nb = LN((inc @ base) @ Wp_ec^T)  (LN positive-scale-invariant)
//   EC's MHA is dead code.
// R9: gemm_ln tiles 64->32 rows (256 thr, 4 waves): grids 192->384 and
// 128->256 blocks — the only two under-filled kernels left (R7/R8 lesson:
// grid >= 256 blocks wins at these shapes). Everything else = R8.
// ============================================================================

#define DEV static __device__ __forceinline__

typedef __attribute__((ext_vector_type(8))) short bf16x8;
typedef __attribute__((ext_vector_type(4))) float f32x4;

DEV uint16_t f2bf(float x){
  union{float f; uint32_t u;} v; v.f=x;
  uint32_t r = v.u + 0x7fffu + ((v.u>>16)&1u);
  return (uint16_t)(r>>16);
}
DEV float bf2f(uint16_t b){
  union{uint32_t u; float f;} v; v.u=((uint32_t)b)<<16; return v.f;
}

#if __has_builtin(__builtin_amdgcn_global_load_lds)
#define HAVE_GLL 1
#else
#define HAVE_GLL 0
#endif

DEV void load_lds16(const uint16_t* g, void* l){
#if HAVE_GLL
  __builtin_amdgcn_global_load_lds((const __attribute__((address_space(1))) uint32_t*)g,
                                   (__attribute__((address_space(3))) uint32_t*)l, 16, 0, 0);
#else
  *(bf16x8*)l = *(const bf16x8*)g;
#endif
}

// ---------------------------------------------------------------------------
// merged prep: blocks [0,12288) = inc prep (f32 copy out + bf16 + bf16^T);
// blocks [12288,14720) = f32->bf16 casts of features + 4 weights.
// ---------------------------------------------------------------------------
__global__ __launch_bounds__(256)
void prep(const float* __restrict__ inc, float* __restrict__ out_inc,
          uint16_t* __restrict__ incb, uint16_t* __restrict__ incT,
          const float* __restrict__ feats, const float* __restrict__ win,
          const float* __restrict__ wout, const float* __restrict__ wpv,
          const float* __restrict__ wpe,
          uint16_t* __restrict__ xb, uint16_t* __restrict__ ow,
          uint16_t* __restrict__ oo, uint16_t* __restrict__ ov,
          uint16_t* __restrict__ oe){
  __shared__ float T[32][33];
  int bx = blockIdx.x;
  int tid = threadIdx.x;
  if (bx < 12288){
    int x = bx % 48;           // e tile
    int t = bx / 48;
    int y = t % 32;            // m tile
    int b = t / 32;            // batch
    int c0 = x*32, r0 = y*32;
    int tx = tid & 31, ty = tid >> 5;
    size_t base = (size_t)b*1024*1536;
#pragma unroll
    for (int j=0;j<4;++j){
      int r = r0 + ty + j*8;
      size_t idx = base + (size_t)r*1536 + c0 + tx;
      float v = inc[idx];
      T[ty+j*8][tx] = v;
      out_inc[idx] = v;
      incb[idx] = f2bf(v);
    }
    __syncthreads();
    size_t baseT = (size_t)b*1536*1024;
#pragma unroll
    for (int j=0;j<4;++j){
      int c = c0 + ty + j*8;
      incT[baseT + (size_t)c*1024 + r0 + tx] = f2bf(T[tx][ty+j*8]);
    }
  } else {
    int i = (bx - 12288)*256 + tid;   // i4 units, total 622592
    const float* src; uint16_t* dst; int j;
    if (i < 524288){ src=feats; dst=xb; j=i; }
    else {
      i -= 524288;
      if (i < 49152){ src=win; dst=ow; j=i; }
      else if (i < 65536){ src=wout; dst=oo; j=i-49152; }
      else if (i < 81920){ src=wpv; dst=ov; j=i-65536; }
      else { src=wpe; dst=oe; j=i-81920; }
    }
    float4 v = ((const float4*)src)[j];
    union { uint16_t u[4]; uint64_t q; } p;
    p.u[0]=f2bf(v.x); p.u[1]=f2bf(v.y); p.u[2]=f2bf(v.z); p.u[3]=f2bf(v.w);
    ((uint64_t*)dst)[j] = p.q;
  }
}

// ---------------------------------------------------------------------------
// NT bf16 GEMM: C[M,N] = A[M,K] * B[N,K]^T (+bias).
// WM: rows/wave = WM*16, M-tile = WM*32. N-tile 128. 256 thr (2x2 waves).
// EPI: 0 = plain (Cf f32 / Cb bf16 row-major)
//      1 = transposed bf16 store (per-batch [N][1024] from flat M=8*1024)
//      2 = row-major store + per-block column exp-sum partials (write-only)
// ---------------------------------------------------------------------------
template<int WM, int BK, int EPI>
__global__ __launch_bounds__(256, 3)
void gemm_nt(const uint16_t* __restrict__ A, const uint16_t* __restrict__ B,
             float* __restrict__ Cf, uint16_t* __restrict__ Cb,
             const float* __restrict__ bias,
             int M, int N, int K, long sA, long sB, long sC,
             float* __restrict__ extra){
  constexpr int AROWS = WM*32;
  constexpr int UPR = BK/8;        // 16B units per row
  constexpr int RPP = 256/UPR;     // rows staged per pass
  __shared__ short As[AROWS*BK];
  __shared__ short Bs[128*BK];
  const int tid = threadIdx.x;
  const int lane = tid & 63;
  const int w = tid >> 6;
  const int wm = w & 1, wn = w >> 1;
  const int r = lane & 15, q = lane >> 4;
  const long zb = blockIdx.z;
  const uint16_t* Ab = A + zb*sA + (size_t)(blockIdx.x*AROWS)*K;
  const uint16_t* Bb = B + zb*sB + (size_t)(blockIdx.y*128)*K;
  f32x4 acc[WM][4];
#pragma unroll
  for (int i=0;i<WM;++i)
#pragma unroll
    for (int j=0;j<4;++j) acc[i][j] = (f32x4){0.f,0.f,0.f,0.f};

  const int srow = tid / UPR;
  const int sblk = tid % UPR;

  for (int kb = 0; kb < K; kb += BK){
#pragma unroll
    for (int i=0;i<AROWS/RPP;++i){
      int row = srow + RPP*i;
      int lblk = sblk ^ (row & (UPR-1));
      load_lds16(Ab + (size_t)row*K + kb + lblk*8, (char*)As + i*4096 + tid*16);
    }
#pragma unroll
    for (int i=0;i<128/RPP;++i){
      int row = srow + RPP*i;
      int lblk = sblk ^ (row & (UPR-1));
      load_lds16(Bb + (size_t)row*K + kb + lblk*8, (char*)Bs + i*4096 + tid*16);
    }
    __syncthreads();
#pragma unroll
    for (int kc=0;kc<BK/32;++kc){
      bf16x8 af[WM], bf[4];
#pragma unroll
      for (int mt=0;mt<WM;++mt){
        int m = wm*(WM*16) + mt*16 + r;
        af[mt] = *(const bf16x8*)&As[m*BK + ((kc*4 + q) ^ (m&(UPR-1)))*8];
      }
#pragma unroll
      for (int nt=0;nt<4;++nt){
        int n = wn*64 + nt*16 + r;
        bf[nt] = *(const bf16x8*)&Bs[n*BK + ((kc*4 + q) ^ (n&(UPR-1)))*8];
      }
#pragma unroll
      for (int mt=0;mt<WM;++mt)
#pragma unroll
        for (int nt=0;nt<4;++nt)
          acc[mt][nt] = __builtin_amdgcn_mfma_f32_16x16x32_bf16(af[mt], bf[nt], acc[mt][nt], 0,0,0);
    }
    __syncthreads();
  }

  const int gm0 = blockIdx.x*AROWS + wm*(WM*16);
  const int gn0 = blockIdx.y*128 + wn*64;

  if constexpr (EPI == 1){
    // transposed bf16: out[b][gn][m'] with b = gm>>10, m' = gm&1023
#pragma unroll
    for (int mt=0;mt<WM;++mt){
      int gmb = gm0 + mt*16 + q*4;           // 4 consecutive rows via reg
      size_t bb_ = (size_t)(gmb>>10)*(256*1024);
      int mm = gmb & 1023;
#pragma unroll
      for (int nt=0;nt<4;++nt){
        int gn = gn0 + nt*16 + r;
        float bv = bias ? bias[gn] : 0.f;
        union{uint16_t u[4]; uint64_t q64;} pk;
#pragma unroll
        for (int reg=0;reg<4;++reg) pk.u[reg] = f2bf(acc[mt][nt][reg] + bv);
        *(uint64_t*)(Cb + bb_ + (size_t)gn*1024 + mm) = pk.q64;
      }
    }
  } else {
#pragma unroll
    for (int mt=0;mt<WM;++mt){
#pragma unroll
      for (int nt=0;nt<4;++nt){
        int gn = gn0 + nt*16 + r;
        float bv = bias ? bias[gn] : 0.f;
#pragma unroll
        for (int reg=0;reg<4;++reg){
          int gm = gm0 + mt*16 + q*4 + reg;   // C/D: col=lane&15, row=quad*4+reg
          float v = acc[mt][nt][reg] + bv;
          size_t off = (size_t)(zb*sC) + (size_t)gm*N + gn;
          if (Cf) Cf[off] = v;
          if (Cb) Cb[off] = f2bf(v);
        }
      }
    }
    if constexpr (EPI == 2){
      // per-block column sums of exp(score) -> extra[(zb*gridDim.x+bx)*256+gn]
      __shared__ float colsum[2][128];
#pragma unroll
      for (int nt=0;nt<4;++nt){
        float s = 0.f;
#pragma unroll
        for (int mt=0;mt<WM;++mt)
#pragma unroll
          for (int reg=0;reg<4;++reg) s += __expf(acc[mt][nt][reg]);
        s += __shfl_xor(s, 16);
        s += __shfl_xor(s, 32);
        if (q == 0) colsum[wm][wn*64 + nt*16 + r] = s;
      }
      __syncthreads();
      if (tid < 128){
        float v = colsum[0][tid] + colsum[1][tid];
        extra[((size_t)zb*gridDim.x + blockIdx.x)*256 + blockIdx.y*128 + tid] = v;
      }
    }
  }
}

// ---------------------------------------------------------------------------
// Edge path: A = p(scores) with p = v*exp(v)/L computed during staging;
// L folded from PART (24 partials/batch) in-kernel. GEMM vs Wpv^T + LN.
// Tile 32m x 256n, BK=64, 256 thr (4 waves, 1 strip each). Grid 384 blocks.
// Writes out_edge f32 + BASET bf16 [b][d][e].
// ---------------------------------------------------------------------------
__global__ __launch_bounds__(256, 4)
void gemm_ln_edge(const uint16_t* __restrict__ SB, const uint16_t* __restrict__ B,
                  const float* __restrict__ part, const float* __restrict__ g,
                  const float* __restrict__ bb, const float* __restrict__ alpha,
                  float* __restrict__ out, uint16_t* __restrict__ baset){
  __shared__ short As[32*64];     // 4 KB
  __shared__ short Bs[256*64];    // 32 KB
  __shared__ float lnS[4][32], lnQ[4][32];
  __shared__ float PLinv[256];
  const int tid = threadIdx.x;
  const int lane = tid & 63;
  const int w = tid >> 6;          // wave = wn strip 0..3
  const int r = lane & 15, q = lane >> 4;
  const int batch = blockIdx.x / 48;

  // fold 24 PART partials -> 1/L
  {
    float s = 0.f;
#pragma unroll
    for (int i=0;i<24;++i) s += part[((size_t)batch*24 + i)*256 + tid];
    PLinv[tid] = 1.0f / s;
  }
  __syncthreads();

  f32x4 acc[2][4];
#pragma unroll
  for (int i=0;i<2;++i)
#pragma unroll
    for (int j=0;j<4;++j) acc[i][j] = (f32x4){0.f,0.f,0.f,0.f};

  const int srow = tid >> 3;   // 0..31
  const int sblk = tid & 7;

  for (int kb = 0; kb < 256; kb += 64){
    // A stage with softmax-apply transform (VGPR path)
    {
      bf16x8 v = *(const bf16x8*)(SB + (size_t)(blockIdx.x*32 + srow)*256 + kb + sblk*8);
      const float* Lp = &PLinv[kb + sblk*8];
      bf16x8 pv;
#pragma unroll
      for (int j=0;j<8;++j){
        float x = bf2f((uint16_t)v[j]);
        pv[j] = (short)f2bf(x * __expf(x) * Lp[j]);
      }
      *(bf16x8*)&As[srow*64 + (sblk ^ (srow&7))*8] = pv;
    }
#pragma unroll
    for (int i=0;i<8;++i){
      int row = srow + 32*i;
      int lblk = sblk ^ (row & 7);
      load_lds16(B + (size_t)row*256 + kb + lblk*8, (char*)Bs + i*4096 + tid*16);
    }
    __syncthreads();
#pragma unroll
    for (int kc=0;kc<2;++kc){
      bf16x8 af[2], bf[4];
#pragma unroll
      for (int mt=0;mt<2;++mt){
        int m = mt*16 + r;
        af[mt] = *(const bf16x8*)&As[m*64 + ((kc*4 + q) ^ (m&7))*8];
      }
#pragma unroll
      for (int nt=0;nt<4;++nt){
        int n = w*64 + nt*16 + r;
        bf[nt] = *(const bf16x8*)&Bs[n*64 + ((kc*4 + q) ^ (n&7))*8];
      }
#pragma unroll
      for (int mt=0;mt<2;++mt)
#pragma unroll
        for (int nt=0;nt<4;++nt)
          acc[mt][nt] = __builtin_amdgcn_mfma_f32_16x16x32_bf16(af[mt], bf[nt], acc[mt][nt], 0,0,0);
    }
    __syncthreads();
  }

  // cross-wave LN reduction
  float rs[2][4], rq[2][4];
#pragma unroll
  for (int mt=0;mt<2;++mt)
#pragma unroll
    for (int reg=0;reg<4;++reg){
      float s=0.f, s2=0.f;
#pragma unroll
      for (int nt=0;nt<4;++nt){
        float v = acc[mt][nt][reg];
        s += v; s2 += v*v;
      }
#pragma unroll
      for (int off=1; off<16; off<<=1){ s += __shfl_xor(s,off); s2 += __shfl_xor(s2,off); }
      rs[mt][reg]=s; rq[mt][reg]=s2;
    }
  if (r == 0){
#pragma unroll
    for (int mt=0;mt<2;++mt)
#pragma unroll
      for (int reg=0;reg<4;++reg){
        int row = mt*16 + q*4 + reg;
        lnS[w][row] = rs[mt][reg];
        lnQ[w][row] = rq[mt][reg];
      }
  }
  __syncthreads();

  const float c0 = 3.0f + alpha[0];
  float mu_[2][4], rstd_[2][4];
#pragma unroll
  for (int mt=0;mt<2;++mt)
#pragma unroll
    for (int reg=0;reg<4;++reg){
      int row = mt*16 + q*4 + reg;
      float S = lnS[0][row]+lnS[1][row]+lnS[2][row]+lnS[3][row];
      float Q = lnQ[0][row]+lnQ[1][row]+lnQ[2][row]+lnQ[3][row];
      float mu = S * (1.f/256.f);
      float var = fmaxf(Q*(1.f/256.f) - mu*mu, 0.f);
      mu_[mt][reg] = mu;
      rstd_[mt][reg] = rsqrtf(var + 1e-5f);
    }

  int e0 = (blockIdx.x % 48) * 32;
#pragma unroll
  for (int mt=0;mt<2;++mt){
#pragma unroll
    for (int nt=0;nt<4;++nt){
      int gn = w*64 + nt*16 + r;
      float gv = g[gn], bv = bb[gn];
      union{uint16_t u[4]; uint64_t q64;} pk;
#pragma unroll
      for (int reg=0;reg<4;++reg){
        int row = mt*16 + q*4 + reg;
        size_t gm = (size_t)blockIdx.x*32 + row;
        float o = ((acc[mt][nt][reg]-mu_[mt][reg])*rstd_[mt][reg]*gv + bv) * c0;
        pk.u[reg] = f2bf(o);
        out[gm*256 + gn] = o;
      }
      int ee = e0 + mt*16 + q*4;
      *(uint64_t*)(baset + ((size_t)batch*256 + gn)*1536 + ee) = pk.q64;
    }
  }
}

// ---------------------------------------------------------------------------
// GEMM + LN/blend (node path): out = cf*feat + cn*LN(A@B^T).
// Tile 32m x 256n, BK=64, 256 thr. Grid 256 blocks.
// ---------------------------------------------------------------------------
__global__ __launch_bounds__(256, 4)
void gemm_ln_node(const uint16_t* __restrict__ A, const uint16_t* __restrict__ B,
                  const float* __restrict__ g, const float* __restrict__ bb,
                  const float* __restrict__ alpha, const float* __restrict__ feats,
                  float* __restrict__ out){
  __shared__ short As[32*64];
  __shared__ short Bs[256*64];
  __shared__ float lnS[4][32], lnQ[4][32];
  const int tid = threadIdx.x;
  const int lane = tid & 63;
  const int w = tid >> 6;
  const int r = lane & 15, q = lane >> 4;
  const uint16_t* Ab = A + (size_t)(blockIdx.x*32)*256;
  f32x4 acc[2][4];
#pragma unroll
  for (int i=0;i<2;++i)
#pragma unroll
    for (int j=0;j<4;++j) acc[i][j] = (f32x4){0.f,0.f,0.f,0.f};

  const int srow = tid >> 3;   // 0..31
  const int sblk = tid & 7;

  for (int kb = 0; kb < 256; kb += 64){
    {
      int lblk = sblk ^ (srow & 7);
      load_lds16(Ab + (size_t)srow*256 + kb + lblk*8, (char*)As + tid*16);
    }
#pragma unroll
    for (int i=0;i<8;++i){
      int row = srow + 32*i;
      int lblk = sblk ^ (row & 7);
      load_lds16(B + (size_t)row*256 + kb + lblk*8, (char*)Bs + i*4096 + tid*16);
    }
    __syncthreads();
#pragma unroll
    for (int kc=0;kc<2;++kc){
      bf16x8 af[2], bf[4];
#pragma unroll
      for (int mt=0;mt<2;++mt){
        int m = mt*16 + r;
        af[mt] = *(const bf16x8*)&As[m*64 + ((kc*4 + q) ^ (m&7))*8];
      }
#pragma unroll
      for (int nt=0;nt<4;++nt){
        int n = w*64 + nt*16 + r;
        bf[nt] = *(const bf16x8*)&Bs[n*64 + ((kc*4 + q) ^ (n&7))*8];
      }
#pragma unroll
      for (int mt=0;mt<2;++mt)
#pragma unroll
        for (int nt=0;nt<4;++nt)
          acc[mt][nt] = __builtin_amdgcn_mfma_f32_16x16x32_bf16(af[mt], bf[nt], acc[mt][nt], 0,0,0);
    }
    __syncthreads();
  }

  float rs[2][4], rq[2][4];
#pragma unroll
  for (int mt=0;mt<2;++mt)
#pragma unroll
    for (int reg=0;reg<4;++reg){
      float s=0.f, s2=0.f;
#pragma unroll
      for (int nt=0;nt<4;++nt){
        float v = acc[mt][nt][reg];
        s += v; s2 += v*v;
      }
#pragma unroll
      for (int off=1; off<16; off<<=1){ s += __shfl_xor(s,off); s2 += __shfl_xor(s2,off); }
      rs[mt][reg]=s; rq[mt][reg]=s2;
    }
  if (r == 0){
#pragma unroll
    for (int mt=0;mt<2;++mt)
#pragma unroll
      for (int reg=0;reg<4;++reg){
        int row = mt*16 + q*4 + reg;
        lnS[w][row] = rs[mt][reg];
        lnQ[w][row] = rq[mt][reg];
      }
  }
  __syncthreads();

  const float a = alpha[0];
  const float ap1 = 1.f + a;
  const float cn = (1.f - a)*(ap1*ap1 + ap1 + 1.f);
  const float cf = ap1*ap1*ap1;

#pragma unroll
  for (int mt=0;mt<2;++mt){
#pragma unroll
    for (int reg=0;reg<4;++reg){
      int row = mt*16 + q*4 + reg;
      float S = lnS[0][row]+lnS[1][row]+lnS[2][row]+lnS[3][row];
      float Q = lnQ[0][row]+lnQ[1][row]+lnQ[2][row]+lnQ[3][row];
      float mu = S * (1.f/256.f);
      float var = fmaxf(Q*(1.f/256.f) - mu*mu, 0.f);
      float rstd = rsqrtf(var + 1e-5f);
      size_t gm = (size_t)blockIdx.x*32 + row;
#pragma unroll
      for (int nt=0;nt<4;++nt){
        int gn = w*64 + nt*16 + r;
        float nv = (acc[mt][nt][reg]-mu)*rstd*g[gn] + bb[gn];
        out[gm*256 + gn] = cf*feats[gm*256+gn] + cn*nv;
      }
    }
  }
}

// ---------------------------------------------------------------------------
// Attention: S^T = K*Q^T (A/B frags interchangeable), packed b64 P-store,
// scalar l. 512 thr = 8 waves x 16 q-rows. grid (8, 64). Max-free softmax.
// ---------------------------------------------------------------------------
DEV void stage_K(short* Kl, const uint16_t* __restrict__ qkv, size_t rowbase,
                 int c, int h, int kr){
  const uint16_t* kp = qkv + ((rowbase + c*256 + kr)*768 + 256 + h*32);
  int sz = (kr&3) ^ ((kr>>2)&1);
#pragma unroll
  for (int lb=0; lb<4; ++lb){
    bf16x8 v = *(const bf16x8*)(kp + lb*8);
    *(bf16x8*)&Kl[kr*32 + ((lb ^ sz))*8] = v;
  }
}

DEV void stage_V(short* VT, const uint16_t* __restrict__ qkv, size_t rowbase,
                 int c, int h, int t){
  int kvp = (t>>1)*2;
  int dhh = (t&1)*16;
  const uint16_t* v0 = qkv + ((rowbase + c*256 + kvp)*768 + 512 + h*32 + dhh);
  const uint16_t* v1 = v0 + 768;
  bf16x8 a0 = *(const bf16x8*)(v0);
  bf16x8 a1 = *(const bf16x8*)(v0+8);
  bf16x8 b0 = *(const bf16x8*)(v1);
  bf16x8 b1 = *(const bf16x8*)(v1+8);
  int blkbase = kvp>>3, off = kvp&7;
#pragma unroll
  for (int i=0;i<8;++i){
    int dh = dhh + i;
    uint32_t pack = (uint32_t)(uint16_t)a0[i] | ((uint32_t)(uint16_t)b0[i]<<16);
    *(uint32_t*)&VT[dh*256 + ((blkbase ^ (dh&7))*8) + off] = pack;
  }
#pragma unroll
  for (int i=0;i<8;++i){
    int dh = dhh + 8 + i;
    uint32_t pack = (uint32_t)(uint16_t)a1[i] | ((uint32_t)(uint16_t)b1[i]<<16);
    *(uint32_t*)&VT[dh*256 + ((blkbase ^ (dh&7))*8) + off] = pack;
  }
}

__global__ __launch_bounds__(512)
void attn_fwd(const uint16_t* __restrict__ qkv, uint16_t* __restrict__ O){
  __shared__ short Kl[256*32];
  __shared__ short VT[32*256];
  __shared__ short Pl[8][16*36];
  const int tid = threadIdx.x, lane = tid&63, w = tid>>6;
  const int r = lane&15, q = lane>>4;
  const int bh = blockIdx.y, b = bh>>3, h = bh&7;
  const int q0 = blockIdx.x*128 + w*16;
  const size_t rowbase = (size_t)b*1024;

  bf16x8 aq;
  {
    const float qscale = 0.17677669529663687f;
    const uint16_t* p = qkv + ((rowbase + q0 + r)*768 + h*32 + q*8);
    bf16x8 t = *(const bf16x8*)p;
#pragma unroll
    for (int j=0;j<8;++j)
      t[j] = (short)f2bf(bf2f((uint16_t)t[j]) * qscale);
    aq = t;
  }

  f32x4 o[2];
  o[0]=(f32x4){0.f,0.f,0.f,0.f}; o[1]=(f32x4){0.f,0.f,0.f,0.f};
  float l = 0.f;

  for (int c=0;c<4;++c){
    __syncthreads();
    if (tid < 256) stage_K(Kl, qkv, rowbase, c, h, tid);
    else           stage_V(VT, qkv, rowbase, c, h, tid-256);
    __syncthreads();
    for (int s32=0; s32<8; ++s32){
#pragma unroll
      for (int t2=0;t2<2;++t2){
        int rn = s32*32 + t2*16 + r;
        int sz = (rn&3) ^ ((rn>>2)&1);
        bf16x8 bk = *(const bf16x8*)&Kl[rn*32 + ((q ^ sz))*8];
        f32x4 z = (f32x4){0.f,0.f,0.f,0.f};
        f32x4 st = __builtin_amdgcn_mfma_f32_16x16x32_bf16(bk, aq, z, 0,0,0);
        union{uint16_t u[4]; uint64_t q64;} pk;
#pragma unroll
        for (int reg=0;reg<4;++reg){
          float p = __expf(st[reg]);
          l += p;
          pk.u[reg] = f2bf(p);
        }
        *(uint64_t*)&Pl[w][r*36 + t2*16 + q*4] = pk.q64;
      }
      bf16x8 bv[2];
#pragma unroll
      for (int db=0;db<2;++db){
        int dh = db*16 + r;
        bv[db] = *(const bf16x8*)&VT[dh*256 + (((s32*4 + q) ^ (dh&7)))*8];
      }
      bf16x8 ap = *(const bf16x8*)&Pl[w][r*36 + q*8];
#pragma unroll
      for (int db=0;db<2;++db)
        o[db] = __builtin_amdgcn_mfma_f32_16x16x32_bf16(ap, bv[db], o[db], 0,0,0);
    }
  }

  l += __shfl_xor(l, 16);
  l += __shfl_xor(l, 32);
#pragma unroll
  for (int db=0;db<2;++db)
#pragma unroll
    for (int reg=0;reg<4;++reg){
      float li = __shfl(l, q*4 + reg);
      int qr = q0 + q*4 + reg;
      O[(rowbase + qr)*256 + h*32 + db*16 + r] = f2bf(o[db][reg] / li);
    }
}

// ===========================================================================
extern "C" void kernel_launch(void* const* d_in, const int* in_sizes, int n_in,
                              void* d_out, int out_size, void* d_ws, size_t ws_size,
                              hipStream_t stream){
  const float* features = (const float*)d_in[0];
  const float* inc      = (const float*)d_in[1];
  const float* vc_Win   = (const float*)d_in[2];
  const float* vc_bin   = (const float*)d_in[3];
  const float* vc_Wout  = (const float*)d_in[4];
  const float* vc_bout  = (const float*)d_in[5];
  const float* vc_Wproj = (const float*)d_in[6];
  const float* vc_ln_g  = (const float*)d_in[7];
  const float* vc_ln_b  = (const float*)d_in[8];
  const float* vc_alpha = (const float*)d_in[9];
  const float* ec_Wproj = (const float*)d_in[14];
  const float* ec_ln_g  = (const float*)d_in[15];
  const float* ec_ln_b  = (const float*)d_in[16];
  const float* ec_alpha = (const float*)d_in[17];

  float* out = (float*)d_out;
  float* out_node = out;                 // [8,1024,256]
  float* out_edge = out + 2097152;       // [8,1536,256]
  float* out_inc  = out + 5242880;       // [8,1024,1536]

  char* ws = (char*)d_ws;
  uint16_t* XB     = (uint16_t*)(ws + 0);          // 4,194,304 (dead after qkv)
  float*    PART   = (float*)   (ws + 0);          // alias: 196,608 (8*24*256)
  uint16_t* WINB   = (uint16_t*)(ws + 4194304);    // 393,216
  uint16_t* WOUTB  = (uint16_t*)(ws + 4587520);    // 131,072
  uint16_t* WPVB   = (uint16_t*)(ws + 4718592);    // 131,072
  uint16_t* WPEB   = (uint16_t*)(ws + 4849664);    // 131,072
  uint16_t* INCB   = (uint16_t*)(ws + 4988928);    // 25,165,824
  uint16_t* INCT   = (uint16_t*)(ws + 30154752);   // 25,165,824
  uint16_t* QKVB   = (uint16_t*)(ws + 55320576);   // 12,582,912
  uint16_t* SCORESB= (uint16_t*)(ws + 55320576);   // alias: QKVB dead after attn
  uint16_t* OB     = (uint16_t*)(ws + 67903488);   // 4,194,304
  uint16_t* ATTNT  = (uint16_t*)(ws + 72097792);   // 4,194,304
  uint16_t* BASET  = (uint16_t*)(ws + 82583552);   // 6,291,456
  uint16_t* W0B    = (uint16_t*)(ws + 88875008);   // 4,194,304  (~93 MB)

  // prep: inc (f32 out + bf16 + bf16^T) and all f32->bf16 casts, one kernel
  prep<<<14720,256,0,stream>>>(inc, out_inc, INCB, INCT,
                               features, vc_Win, vc_Wout, vc_Wproj, ec_Wproj,
                               XB, WINB, WOUTB, WPVB, WPEB);

  // MHA(features): qkv -> attention -> out-proj (writes ATTNT transposed)
  gemm_nt<4,64,0><<<dim3(64,6,1),256,0,stream>>>(XB, WINB, nullptr, QKVB, vc_bin,
                                                 8192,768,256, 0,0,0, nullptr);
  attn_fwd<<<dim3(8,64),512,0,stream>>>(QKVB, OB);
  gemm_nt<2,128,1><<<dim3(128,2,1),256,0,stream>>>(OB, WOUTB, nullptr, ATTNT, vc_bout,
                                                   8192,256,256, 0,0,0, nullptr);

  // scores = inc^T @ attn -> bf16, with per-block column exp-sum partials
  gemm_nt<2,128,2><<<dim3(24,2,8),256,0,stream>>>(INCT, ATTNT, nullptr, SCORESB, nullptr,
                                                  1536,256,1024,
                                                  1536L*1024, 256L*1024, 1536L*256, PART);

  // edge path fully fused: PART->1/L, p=v*exp(v)/L staging, GEMM, LN,
  // out_edge f32 + BASET bf16 transposed. 384 blocks.
  gemm_ln_edge<<<384,256,0,stream>>>(SCORESB, WPVB, PART, vc_ln_g, vc_ln_b,
                                     vc_alpha, out_edge, BASET);

  // node path: W0 = inc @ base, project + fused LN/blend. 256 blocks.
  gemm_nt<2,128,0><<<dim3(16,2,8),256,0,stream>>>(INCB, BASET, nullptr, W0B, nullptr,
                                                  1024,256,1536,
                                                  1024L*1536, 256L*1536, 1024L*256, nullptr);
  gemm_ln_node<<<256,256,0,stream>>>(W0B, WPEB, ec_ln_g, ec_ln_b, ec_alpha,
                                     features, out_node);
}